// Round 1
// baseline (2791.086 us; speedup 1.0000x reference)
//
#include <hip/hip_runtime.h>

#define H_DIM 1024
#define NHEAD 16
#define HDIM  64
#define BATCH 2
#define SEQ   2048
#define MTOT  (BATCH*SEQ)   // 4096

// ---------------------------------------------------------------------------
// GEMM: C[m][n] = sum_k A[m][k] * W[n][k] + bias[n]   (torch Linear: x @ W^T + b)
// M=4096, N=1024, K=1024 fixed. 64x64 block tile, 256 threads, 4x4 micro-tile.
// ---------------------------------------------------------------------------
__global__ __launch_bounds__(256) void gemm_bias_kernel(
    const float* __restrict__ A, const float* __restrict__ W,
    const float* __restrict__ bias, float* __restrict__ C) {
  const int K = H_DIM, N = H_DIM;
  __shared__ float As[64][17];   // [m][k], pad +1
  __shared__ float Ws[64][17];   // [n][k], pad +1
  const int tx = threadIdx.x & 15, ty = threadIdx.x >> 4;
  const int m0 = blockIdx.y * 64, n0 = blockIdx.x * 64;
  float acc[4][4] = {};

  for (int k0 = 0; k0 < K; k0 += 16) {
#pragma unroll
    for (int i = 0; i < 4; i++) {
      int idx = threadIdx.x + i * 256;       // 0..1023
      int kk = idx & 15, mm = idx >> 4;      // consecutive lanes -> consecutive k (64B segments)
      As[mm][kk] = A[(size_t)(m0 + mm) * K + k0 + kk];
      Ws[mm][kk] = W[(size_t)(n0 + mm) * K + k0 + kk];
    }
    __syncthreads();
#pragma unroll
    for (int kk = 0; kk < 16; kk++) {
      float a[4], b[4];
#pragma unroll
      for (int i = 0; i < 4; i++) a[i] = As[ty * 4 + i][kk];  // broadcast across tx
#pragma unroll
      for (int j = 0; j < 4; j++) b[j] = Ws[tx * 4 + j][kk];  // 2-way conflict = free
#pragma unroll
      for (int i = 0; i < 4; i++)
#pragma unroll
        for (int j = 0; j < 4; j++)
          acc[i][j] = fmaf(a[i], b[j], acc[i][j]);
    }
    __syncthreads();
  }

#pragma unroll
  for (int i = 0; i < 4; i++) {
    int m = m0 + ty * 4 + i;
    float4 o;
    o.x = acc[i][0] + bias[n0 + tx * 4 + 0];
    o.y = acc[i][1] + bias[n0 + tx * 4 + 1];
    o.z = acc[i][2] + bias[n0 + tx * 4 + 2];
    o.w = acc[i][3] + bias[n0 + tx * 4 + 3];
    *(float4*)&C[(size_t)m * N + n0 + tx * 4] = o;
  }
}

// ---------------------------------------------------------------------------
// Flash-style attention. One thread per query row; QB=128 rows per block,
// 128 threads. K/V tiles of 64 rows staged in LDS. Online softmax.
// q,k,v layout: [B*S][H] (head h occupies cols h*64..h*64+63).
// ctx written in the same layout.
// ---------------------------------------------------------------------------
#define QB 128
#define KB 64

__global__ __launch_bounds__(128) void attn_kernel(
    const float* __restrict__ q, const float* __restrict__ k,
    const float* __restrict__ v, float* __restrict__ ctx) {
  __shared__ float Qs[QB][HDIM + 1];   // pad +1: conflict-free per-row scalar reads
  __shared__ float Ks[KB][HDIM];       // uniform (broadcast) access, no pad needed
  __shared__ float Vs[KB][HDIM];

  const int t = threadIdx.x;
  const int nqt = SEQ / QB;                  // 16
  const int qt = blockIdx.x & (nqt - 1);
  const int h  = (blockIdx.x / nqt) & (NHEAD - 1);
  const int b  = blockIdx.x / (nqt * NHEAD);
  const int q0 = qt * QB;
  const size_t headoff = (size_t)h * HDIM;

  // ---- load Q tile: 128x64 floats = 2048 float4, 16 per thread ----
#pragma unroll
  for (int i = 0; i < 16; i++) {
    int idx = t + i * 128;                   // float4 index
    int c4 = idx & 15, r = idx >> 4;
    float4 g = *(const float4*)&q[(size_t)(b * SEQ + q0 + r) * H_DIM + headoff + c4 * 4];
    Qs[r][c4 * 4 + 0] = g.x;
    Qs[r][c4 * 4 + 1] = g.y;
    Qs[r][c4 * 4 + 2] = g.z;
    Qs[r][c4 * 4 + 3] = g.w;
  }

  float O[HDIM];
#pragma unroll
  for (int d = 0; d < HDIM; d++) O[d] = 0.f;
  float m = -1e30f, l = 0.f;
  const float scale = 0.125f;                // 1/sqrt(64)

  for (int k0 = 0; k0 < SEQ; k0 += KB) {
    __syncthreads();   // protect Ks/Vs (prev iter still reading) + Qs on first iter
    // ---- stage K,V tile: 64x64 floats = 1024 float4, 8 per thread each ----
#pragma unroll
    for (int i = 0; i < 8; i++) {
      int idx = t + i * 128;
      int c4 = idx & 15, r = idx >> 4;
      size_t g = (size_t)(b * SEQ + k0 + r) * H_DIM + headoff + c4 * 4;
      *(float4*)&Ks[r][c4 * 4] = *(const float4*)&k[g];
      *(float4*)&Vs[r][c4 * 4] = *(const float4*)&v[g];
    }
    __syncthreads();

    // ---- scores: sc[c] = Q[t] . K[c] ----
    float sc[KB];
#pragma unroll
    for (int c = 0; c < KB; c++) sc[c] = 0.f;
#pragma unroll
    for (int dc = 0; dc < HDIM / 16; dc++) {
      float qr[16];
#pragma unroll
      for (int j = 0; j < 16; j++) qr[j] = Qs[t][dc * 16 + j];
#pragma unroll
      for (int c = 0; c < KB; c++) {
        float s = sc[c];
#pragma unroll
        for (int j4 = 0; j4 < 4; j4++) {
          float4 kv = *(const float4*)&Ks[c][dc * 16 + j4 * 4];
          s = fmaf(qr[j4 * 4 + 0], kv.x, s);
          s = fmaf(qr[j4 * 4 + 1], kv.y, s);
          s = fmaf(qr[j4 * 4 + 2], kv.z, s);
          s = fmaf(qr[j4 * 4 + 3], kv.w, s);
        }
        sc[c] = s;
      }
    }

    // ---- online softmax update ----
    float tmax = -1e30f;
#pragma unroll
    for (int c = 0; c < KB; c++) {
      sc[c] *= scale;
      tmax = fmaxf(tmax, sc[c]);
    }
    float mnew = fmaxf(m, tmax);
    float f = __expf(m - mnew);              // 0 on first iter (m=-1e30)
    l *= f;
#pragma unroll
    for (int d = 0; d < HDIM; d++) O[d] *= f;
#pragma unroll
    for (int c = 0; c < KB; c++) {
      float p = __expf(sc[c] - mnew);
      l += p;
      sc[c] = p;
    }
    m = mnew;

    // ---- PV accumulate ----
#pragma unroll
    for (int c = 0; c < KB; c++) {
      float p = sc[c];
#pragma unroll
      for (int d4 = 0; d4 < HDIM / 4; d4++) {
        float4 vv = *(const float4*)&Vs[c][d4 * 4];
        O[d4 * 4 + 0] = fmaf(p, vv.x, O[d4 * 4 + 0]);
        O[d4 * 4 + 1] = fmaf(p, vv.y, O[d4 * 4 + 1]);
        O[d4 * 4 + 2] = fmaf(p, vv.z, O[d4 * 4 + 2]);
        O[d4 * 4 + 3] = fmaf(p, vv.w, O[d4 * 4 + 3]);
      }
    }
  }

  // ---- epilogue ----
  float inv = 1.f / l;
  size_t obase = (size_t)(b * SEQ + q0 + t) * H_DIM + headoff;
#pragma unroll
  for (int d4 = 0; d4 < HDIM / 4; d4++) {
    float4 o;
    o.x = O[d4 * 4 + 0] * inv;
    o.y = O[d4 * 4 + 1] * inv;
    o.z = O[d4 * 4 + 2] * inv;
    o.w = O[d4 * 4 + 3] * inv;
    *(float4*)&ctx[obase + d4 * 4] = o;
  }
}

// ---------------------------------------------------------------------------
extern "C" void kernel_launch(void* const* d_in, const int* in_sizes, int n_in,
                              void* d_out, int out_size, void* d_ws, size_t ws_size,
                              hipStream_t stream) {
  const float* x  = (const float*)d_in[0];
  const float* Wq = (const float*)d_in[1];
  const float* bq = (const float*)d_in[2];
  const float* Wk = (const float*)d_in[3];
  const float* bk = (const float*)d_in[4];
  const float* Wv = (const float*)d_in[5];
  const float* bv = (const float*)d_in[6];
  const float* Wo = (const float*)d_in[7];
  const float* bo = (const float*)d_in[8];
  float* out = (float*)d_out;

  float* ws = (float*)d_ws;
  const size_t planes = (size_t)MTOT * H_DIM;  // 4M floats = 16.78 MB
  float* qb = ws;
  float* kb = ws + planes;
  float* vb = ws + 2 * planes;
  float* cb = ws + 3 * planes;

  dim3 gg(H_DIM / 64, MTOT / 64);   // (16, 64)
  gemm_bias_kernel<<<gg, 256, 0, stream>>>(x, Wq, bq, qb);
  gemm_bias_kernel<<<gg, 256, 0, stream>>>(x, Wk, bk, kb);
  gemm_bias_kernel<<<gg, 256, 0, stream>>>(x, Wv, bv, vb);

  attn_kernel<<<dim3(BATCH * NHEAD * (SEQ / QB)), QB, 0, stream>>>(qb, kb, vb, cb);

  gemm_bias_kernel<<<gg, 256, 0, stream>>>(cb, Wo, bo, out);
}

// Round 2
// 1020.056 us; speedup vs baseline: 2.7362x; 2.7362x over previous
//
#include <hip/hip_runtime.h>
#include <hip/hip_bf16.h>

#define H_DIM 1024
#define NHEAD 16
#define HDIM  64
#define BATCH 2
#define SEQ   2048
#define MTOT  (BATCH*SEQ)   // 4096

typedef __bf16 bf16x8 __attribute__((ext_vector_type(8)));
typedef float  f32x4  __attribute__((ext_vector_type(4)));
typedef short  short8 __attribute__((ext_vector_type(8)));

static __device__ __forceinline__ unsigned short f2bf(float f) {
  __hip_bfloat16 h = __float2bfloat16(f);   // RNE
  return __builtin_bit_cast(unsigned short, h);
}

// ---------------------------------------------------------------------------
// GEMM: C[m][n] = (sum_k A[m][k] * W[n][k] + bias[n]) * outScale
// M=4096, N=K=1024. 64x64 tile, 256 threads, 4x4 micro-tile. fp32 compute.
// BF16OUT: pack 4 bf16 (8B store) into Cb; else float4 into Cf.
// ---------------------------------------------------------------------------
template <bool BF16OUT>
__global__ __launch_bounds__(256) void gemm_bias_kernel(
    const float* __restrict__ A, const float* __restrict__ W,
    const float* __restrict__ bias, float* __restrict__ Cf,
    unsigned short* __restrict__ Cb, float outScale) {
  const int K = H_DIM, N = H_DIM;
  __shared__ float As[64][17];
  __shared__ float Ws[64][17];
  const int tx = threadIdx.x & 15, ty = threadIdx.x >> 4;
  const int m0 = blockIdx.y * 64, n0 = blockIdx.x * 64;
  float acc[4][4] = {};

  for (int k0 = 0; k0 < K; k0 += 16) {
#pragma unroll
    for (int i = 0; i < 4; i++) {
      int idx = threadIdx.x + i * 256;
      int kk = idx & 15, mm = idx >> 4;
      As[mm][kk] = A[(size_t)(m0 + mm) * K + k0 + kk];
      Ws[mm][kk] = W[(size_t)(n0 + mm) * K + k0 + kk];
    }
    __syncthreads();
#pragma unroll
    for (int kk = 0; kk < 16; kk++) {
      float a[4], b[4];
#pragma unroll
      for (int i = 0; i < 4; i++) a[i] = As[ty * 4 + i][kk];
#pragma unroll
      for (int j = 0; j < 4; j++) b[j] = Ws[tx * 4 + j][kk];
#pragma unroll
      for (int i = 0; i < 4; i++)
#pragma unroll
        for (int j = 0; j < 4; j++)
          acc[i][j] = fmaf(a[i], b[j], acc[i][j]);
    }
    __syncthreads();
  }

#pragma unroll
  for (int i = 0; i < 4; i++) {
    int m = m0 + ty * 4 + i;
    float vals[4];
#pragma unroll
    for (int j = 0; j < 4; j++)
      vals[j] = (acc[i][j] + bias[n0 + tx * 4 + j]) * outScale;
    if constexpr (BF16OUT) {
      uint2 u;
      u.x = ((unsigned)f2bf(vals[1]) << 16) | f2bf(vals[0]);
      u.y = ((unsigned)f2bf(vals[3]) << 16) | f2bf(vals[2]);
      *(uint2*)&Cb[(size_t)m * N + n0 + tx * 4] = u;
    } else {
      float4 o = {vals[0], vals[1], vals[2], vals[3]};
      *(float4*)&Cf[(size_t)m * N + n0 + tx * 4] = o;
    }
  }
}

// ---------------------------------------------------------------------------
// MFMA flash attention. Block = 256 thr = 4 waves; 128 q-rows/block (32/wave).
// KV tiles of 64. bf16 q/k/v (scale pre-folded into q), fp32 softmax + accum.
// mfma_f32_16x16x32_bf16:
//   A: lane holds row=(l&15), k=(l>>4)*8+j (8 contiguous bf16)
//   B: lane holds col=(l&15), k=(l>>4)*8+j
//   C: lane holds col=(l&15), row=(l>>4)*4+reg
// ---------------------------------------------------------------------------
#define QB 128
#define KB 64
#define LDK 72   // padded LDS row (bf16 elems) = 144B, 16B-aligned rows

__global__ __launch_bounds__(256) void attn_mfma_kernel(
    const unsigned short* __restrict__ q, const unsigned short* __restrict__ k,
    const unsigned short* __restrict__ v, float* __restrict__ ctx) {
  __shared__ unsigned short Ks[KB][LDK];
  __shared__ unsigned short Vt[HDIM][LDK];   // Vt[d][key]
  __shared__ unsigned short Qs[QB][LDK];     // Q at init; per-wave P buffer in loop

  const int tid = threadIdx.x;
  const int w  = tid >> 6;
  const int l  = tid & 63;
  const int lg = l >> 4;   // lane group 0..3
  const int lc = l & 15;   // lane col   0..15
  const int qt = blockIdx.x & 15;
  const int h  = (blockIdx.x >> 4) & 15;
  const int b  = blockIdx.x >> 8;

  // ---- stage Q tile (128 rows x 64 bf16): 1024 x 16B chunks, 4/thread ----
  {
    const size_t qbase = ((size_t)(b * SEQ + qt * QB)) * H_DIM + h * HDIM;
#pragma unroll
    for (int i = 0; i < 4; i++) {
      int c = tid + i * 256;
      int r = c >> 3, cc = c & 7;
      *(short8*)&Qs[r][cc * 8] = *(const short8*)&q[qbase + (size_t)r * H_DIM + cc * 8];
    }
  }
  __syncthreads();
  bf16x8 qf[2][2];
#pragma unroll
  for (int qi = 0; qi < 2; qi++)
#pragma unroll
    for (int kt = 0; kt < 2; kt++)
      qf[qi][kt] = *(bf16x8*)&Qs[w * 32 + qi * 16 + lc][kt * 32 + lg * 8];
  __syncthreads();   // all q-frags read before Qs is reused as P

  f32x4 Oacc[2][4];
  float mrow[2][4], lrow[2][4];
#pragma unroll
  for (int qi = 0; qi < 2; qi++)
#pragma unroll
    for (int dj = 0; dj < 4; dj++)
      Oacc[qi][dj] = (f32x4){0.f, 0.f, 0.f, 0.f};
#pragma unroll
  for (int qi = 0; qi < 2; qi++)
#pragma unroll
    for (int r = 0; r < 4; r++) { mrow[qi][r] = -1e30f; lrow[qi][r] = 0.f; }

  unsigned short* Pw = &Qs[w * 32][0];   // per-wave 32x72 P buffer

  for (int t = 0; t < SEQ / KB; t++) {
    __syncthreads();   // prev-iter Ks/Vt reads done
    const size_t kvbase = ((size_t)(b * SEQ + t * KB)) * H_DIM + h * HDIM;
    // ---- stage K row-major: 512 chunks, 2/thread ----
#pragma unroll
    for (int i = 0; i < 2; i++) {
      int c = tid + i * 256;
      int r = c >> 3, cc = c & 7;
      *(short8*)&Ks[r][cc * 8] = *(const short8*)&k[kvbase + (size_t)r * H_DIM + cc * 8];
    }
    // ---- stage V transposed; rotate write order by cc -> 2-way banks ----
#pragma unroll
    for (int i = 0; i < 2; i++) {
      int c = tid + i * 256;
      int key = c >> 3, cc = c & 7;
      short8 vv = *(const short8*)&v[kvbase + (size_t)key * H_DIM + cc * 8];
#pragma unroll
      for (int jj = 0; jj < 8; jj++) {
        int j = (jj + cc) & 7;
        Vt[cc * 8 + j][key] = (unsigned short)vv[j];
      }
    }
    __syncthreads();

    // ---- S = Q K^T : per wave 2x4 tiles of 16x16, K-dim 64 in 2 steps ----
    f32x4 sc[2][4];
#pragma unroll
    for (int qi = 0; qi < 2; qi++)
#pragma unroll
      for (int kj = 0; kj < 4; kj++) {
        f32x4 s = (f32x4){0.f, 0.f, 0.f, 0.f};
#pragma unroll
        for (int kt = 0; kt < 2; kt++) {
          bf16x8 bfrag = *(bf16x8*)&Ks[kj * 16 + lc][kt * 32 + lg * 8];
          s = __builtin_amdgcn_mfma_f32_16x16x32_bf16(qf[qi][kt], bfrag, s, 0, 0, 0);
        }
        sc[qi][kj] = s;
      }

    // ---- online softmax (fp32) ----
#pragma unroll
    for (int qi = 0; qi < 2; qi++) {
      float tm[4];
#pragma unroll
      for (int r = 0; r < 4; r++) {
        tm[r] = fmaxf(fmaxf(sc[qi][0][r], sc[qi][1][r]),
                      fmaxf(sc[qi][2][r], sc[qi][3][r]));
      }
#pragma unroll
      for (int mm = 1; mm < 16; mm <<= 1)
#pragma unroll
        for (int r = 0; r < 4; r++)
          tm[r] = fmaxf(tm[r], __shfl_xor(tm[r], mm));
#pragma unroll
      for (int r = 0; r < 4; r++) {
        float mnew = fmaxf(mrow[qi][r], tm[r]);
        float f = __expf(mrow[qi][r] - mnew);
        mrow[qi][r] = mnew;
        lrow[qi][r] *= f;
#pragma unroll
        for (int dj = 0; dj < 4; dj++) Oacc[qi][dj][r] *= f;
      }
      // p = exp(s - m); write bf16 P (rotate kj by lane group -> 2-way banks)
#pragma unroll
      for (int kjj = 0; kjj < 4; kjj++) {
        int kj = (kjj + lg) & 3;
#pragma unroll
        for (int r = 0; r < 4; r++) {
          float p = __expf(sc[qi][kj][r] - mrow[qi][r]);
          lrow[qi][r] += p;
          Pw[(qi * 16 + lg * 4 + r) * LDK + kj * 16 + lc] = f2bf(p);
        }
      }
    }

    // ---- O += P V ----
    bf16x8 vfrag[4][2];
#pragma unroll
    for (int dj = 0; dj < 4; dj++)
#pragma unroll
      for (int kt = 0; kt < 2; kt++)
        vfrag[dj][kt] = *(bf16x8*)&Vt[dj * 16 + lc][kt * 32 + lg * 8];
#pragma unroll
    for (int qi = 0; qi < 2; qi++) {
      bf16x8 pa[2];
#pragma unroll
      for (int kt = 0; kt < 2; kt++)
        pa[kt] = *(bf16x8*)&Pw[(qi * 16 + lc) * LDK + kt * 32 + lg * 8];
#pragma unroll
      for (int dj = 0; dj < 4; dj++)
#pragma unroll
        for (int kt = 0; kt < 2; kt++)
          Oacc[qi][dj] = __builtin_amdgcn_mfma_f32_16x16x32_bf16(pa[kt], vfrag[dj][kt],
                                                                 Oacc[qi][dj], 0, 0, 0);
    }
  }

  // ---- epilogue: normalize and store fp32 ctx ----
#pragma unroll
  for (int qi = 0; qi < 2; qi++) {
    float inv[4];
#pragma unroll
    for (int r = 0; r < 4; r++) {
      float ls = lrow[qi][r];
#pragma unroll
      for (int mm = 1; mm < 16; mm <<= 1) ls += __shfl_xor(ls, mm);
      inv[r] = 1.f / ls;
    }
#pragma unroll
    for (int dj = 0; dj < 4; dj++)
#pragma unroll
      for (int r = 0; r < 4; r++) {
        int qrow = b * SEQ + qt * QB + w * 32 + qi * 16 + lg * 4 + r;
        ctx[(size_t)qrow * H_DIM + h * HDIM + dj * 16 + lc] = Oacc[qi][dj][r] * inv[r];
      }
  }
}

// ---------------------------------------------------------------------------
extern "C" void kernel_launch(void* const* d_in, const int* in_sizes, int n_in,
                              void* d_out, int out_size, void* d_ws, size_t ws_size,
                              hipStream_t stream) {
  const float* x  = (const float*)d_in[0];
  const float* Wq = (const float*)d_in[1];
  const float* bq = (const float*)d_in[2];
  const float* Wk = (const float*)d_in[3];
  const float* bk = (const float*)d_in[4];
  const float* Wv = (const float*)d_in[5];
  const float* bv = (const float*)d_in[6];
  const float* Wo = (const float*)d_in[7];
  const float* bo = (const float*)d_in[8];
  float* out = (float*)d_out;

  const size_t plane = (size_t)MTOT * H_DIM;
  unsigned short* qb = (unsigned short*)d_ws;         // bf16 planes
  unsigned short* kb = qb + plane;
  unsigned short* vb = kb + plane;
  float* cb = (float*)(vb + plane);                   // fp32 ctx

  dim3 gg(H_DIM / 64, MTOT / 64);   // (16, 64)
  // scale 1/sqrt(64) folded into the Q projection (before bf16 rounding)
  gemm_bias_kernel<true ><<<gg, 256, 0, stream>>>(x, Wq, bq, nullptr, qb, 0.125f);
  gemm_bias_kernel<true ><<<gg, 256, 0, stream>>>(x, Wk, bk, nullptr, kb, 1.0f);
  gemm_bias_kernel<true ><<<gg, 256, 0, stream>>>(x, Wv, bv, nullptr, vb, 1.0f);

  attn_mfma_kernel<<<dim3(BATCH * NHEAD * (SEQ / QB)), 256, 0, stream>>>(qb, kb, vb, cb);

  gemm_bias_kernel<false><<<gg, 256, 0, stream>>>(cb, Wo, bo, out, nullptr, 1.0f);
}

// Round 3
// 416.325 us; speedup vs baseline: 6.7041x; 2.4501x over previous
//
#include <hip/hip_runtime.h>
#include <hip/hip_bf16.h>

#define H_DIM 1024
#define NHEAD 16
#define HDIM  64
#define BATCH 2
#define SEQ   2048
#define MTOT  (BATCH*SEQ)   // 4096

typedef __bf16 bf16x8 __attribute__((ext_vector_type(8)));
typedef float  f32x4  __attribute__((ext_vector_type(4)));
typedef short  short8 __attribute__((ext_vector_type(8)));
typedef unsigned short u16;

static __device__ __forceinline__ u16 f2bf(float f) {
  __hip_bfloat16 h = __float2bfloat16(f);   // RNE
  return __builtin_bit_cast(u16, h);
}
static __device__ __forceinline__ float bf2f(u16 u) {
  return __builtin_bit_cast(float, (unsigned)u << 16);
}

// async global->LDS, 16B per lane. LDS dest = wave-uniform base + lane*16.
static __device__ __forceinline__ void load_lds16(const void* g, void* l) {
  __builtin_amdgcn_global_load_lds(
      (const __attribute__((address_space(1))) unsigned int*)g,
      (__attribute__((address_space(3))) unsigned int*)l, 16, 0, 0);
}

// ---------------------------------------------------------------------------
// fp32 -> bf16 conversion (8 elems/thread)
// ---------------------------------------------------------------------------
__global__ __launch_bounds__(256) void conv_bf16(
    const float* __restrict__ in, u16* __restrict__ out, int n8) {
  int i = blockIdx.x * 256 + threadIdx.x;
  if (i >= n8) return;
  float4 a = ((const float4*)in)[i * 2];
  float4 b = ((const float4*)in)[i * 2 + 1];
  union { u16 u[8]; short8 s; } r;
  r.u[0] = f2bf(a.x); r.u[1] = f2bf(a.y); r.u[2] = f2bf(a.z); r.u[3] = f2bf(a.w);
  r.u[4] = f2bf(b.x); r.u[5] = f2bf(b.y); r.u[6] = f2bf(b.z); r.u[7] = f2bf(b.w);
  *(short8*)&out[i * 8] = r.s;
}

// fp32 -> split bf16 (hi + lo), 8 elems/thread
__global__ __launch_bounds__(256) void conv_split(
    const float* __restrict__ in, u16* __restrict__ hi, u16* __restrict__ lo, int n8) {
  int i = blockIdx.x * 256 + threadIdx.x;
  if (i >= n8) return;
  float v[8];
  float4 a = ((const float4*)in)[i * 2];
  float4 b = ((const float4*)in)[i * 2 + 1];
  v[0] = a.x; v[1] = a.y; v[2] = a.z; v[3] = a.w;
  v[4] = b.x; v[5] = b.y; v[6] = b.z; v[7] = b.w;
  union { u16 u[8]; short8 s; } rh, rl;
#pragma unroll
  for (int j = 0; j < 8; j++) {
    u16 h = f2bf(v[j]);
    rh.u[j] = h;
    rl.u[j] = f2bf(v[j] - bf2f(h));
  }
  *(short8*)&hi[i * 8] = rh.s;
  *(short8*)&lo[i * 8] = rl.s;
}

// ---------------------------------------------------------------------------
// QKV fused GEMM (m97 structure): C[m][n] = sum_k X[m][k]*W3[n][k], bf16 MFMA.
// M=4096, N=3072 (q|k|v), K=1024. 128x128 tile, BK=32, 4 waves (2x2), each
// wave 64x64 = 4x4 frags of 16x16. Output: bf16 planes with bias+scale.
// ---------------------------------------------------------------------------
#define BK 32

__global__ __launch_bounds__(256) void gemm_qkv(
    const u16* __restrict__ Xb, const u16* __restrict__ W3,
    const float* __restrict__ bq, const float* __restrict__ bk2,
    const float* __restrict__ bv,
    u16* __restrict__ qp, u16* __restrict__ kp, u16* __restrict__ vp) {
  __shared__ __align__(16) u16 Al[128 * BK];   // [m][k] linear, 8KB
  __shared__ __align__(16) u16 Bl[128 * BK];   // [n][k] linear, 8KB
  const int tid = threadIdx.x;
  const int w = tid >> 6, l = tid & 63, lg = l >> 4, lc = l & 15;
  const int wr = w >> 1, wc = w & 1;
  const int m0 = blockIdx.y * 128, n0 = blockIdx.x * 128;
  const int sr = w * 16 + (l >> 2);   // staging row within 64-row half
  const int sc = (l & 3) * 8;         // staging col (bf16 elems)

  f32x4 acc[4][4];
#pragma unroll
  for (int i = 0; i < 4; i++)
#pragma unroll
    for (int j = 0; j < 4; j++) acc[i][j] = (f32x4){0.f, 0.f, 0.f, 0.f};

  for (int k0 = 0; k0 < H_DIM; k0 += BK) {
    __syncthreads();   // prev frag reads done before overwrite
    load_lds16(&Xb[(size_t)(m0 + sr) * H_DIM + k0 + sc],      &Al[w * 512]);
    load_lds16(&Xb[(size_t)(m0 + 64 + sr) * H_DIM + k0 + sc], &Al[2048 + w * 512]);
    load_lds16(&W3[(size_t)(n0 + sr) * H_DIM + k0 + sc],      &Bl[w * 512]);
    load_lds16(&W3[(size_t)(n0 + 64 + sr) * H_DIM + k0 + sc], &Bl[2048 + w * 512]);
    __syncthreads();   // vmcnt drained by compiler before barrier

    bf16x8 af[4], bfr[4];
#pragma unroll
    for (int mi = 0; mi < 4; mi++)
      af[mi] = *(const bf16x8*)&Al[(wr * 64 + mi * 16 + lc) * BK + lg * 8];
#pragma unroll
    for (int nj = 0; nj < 4; nj++)
      bfr[nj] = *(const bf16x8*)&Bl[(wc * 64 + nj * 16 + lc) * BK + lg * 8];
#pragma unroll
    for (int mi = 0; mi < 4; mi++)
#pragma unroll
      for (int nj = 0; nj < 4; nj++)
        acc[mi][nj] = __builtin_amdgcn_mfma_f32_16x16x32_bf16(af[mi], bfr[nj],
                                                              acc[mi][nj], 0, 0, 0);
  }

  // epilogue: bias + scale, bf16 store into the right plane
  const int np = n0 >> 10;   // uniform per block (128 | 1024)
  u16* outp = np == 0 ? qp : (np == 1 ? kp : vp);
  const float* bias = np == 0 ? bq : (np == 1 ? bk2 : bv);
  const float scale = np == 0 ? 0.125f : 1.0f;   // 1/sqrt(64) folded into q
  const int nc0 = (n0 & 1023) + wc * 64;
  float bvals[4];
#pragma unroll
  for (int nj = 0; nj < 4; nj++) bvals[nj] = bias[nc0 + nj * 16 + lc];
#pragma unroll
  for (int mi = 0; mi < 4; mi++)
#pragma unroll
    for (int nj = 0; nj < 4; nj++)
#pragma unroll
      for (int r = 0; r < 4; r++) {
        int row = m0 + wr * 64 + mi * 16 + lg * 4 + r;   // C: col=l&15, row=(l>>4)*4+r
        outp[(size_t)row * 1024 + nc0 + nj * 16 + lc] =
            f2bf((acc[mi][nj][r] + bvals[nj]) * scale);
      }
}

// ---------------------------------------------------------------------------
// O-projection, split-bf16 (hi+lo): out = Ah@Bh + Ah@Bl + Al@Bh + bias, fp32 out.
// M=4096, N=1024, K=1024. Same m97 structure, 4 LDS tiles, 48 MFMA/K-step.
// ---------------------------------------------------------------------------
__global__ __launch_bounds__(256) void gemm_oproj(
    const u16* __restrict__ Ah, const u16* __restrict__ Alo,
    const u16* __restrict__ Bh, const u16* __restrict__ Blo,
    const float* __restrict__ bias, float* __restrict__ out) {
  __shared__ __align__(16) u16 sAh[128 * BK];
  __shared__ __align__(16) u16 sAl[128 * BK];
  __shared__ __align__(16) u16 sBh[128 * BK];
  __shared__ __align__(16) u16 sBl[128 * BK];
  const int tid = threadIdx.x;
  const int w = tid >> 6, l = tid & 63, lg = l >> 4, lc = l & 15;
  const int wr = w >> 1, wc = w & 1;
  const int m0 = blockIdx.y * 128, n0 = blockIdx.x * 128;
  const int sr = w * 16 + (l >> 2);
  const int sc = (l & 3) * 8;

  f32x4 acc[4][4];
#pragma unroll
  for (int i = 0; i < 4; i++)
#pragma unroll
    for (int j = 0; j < 4; j++) acc[i][j] = (f32x4){0.f, 0.f, 0.f, 0.f};

  for (int k0 = 0; k0 < H_DIM; k0 += BK) {
    __syncthreads();
    load_lds16(&Ah [(size_t)(m0 + sr) * H_DIM + k0 + sc],      &sAh[w * 512]);
    load_lds16(&Ah [(size_t)(m0 + 64 + sr) * H_DIM + k0 + sc], &sAh[2048 + w * 512]);
    load_lds16(&Alo[(size_t)(m0 + sr) * H_DIM + k0 + sc],      &sAl[w * 512]);
    load_lds16(&Alo[(size_t)(m0 + 64 + sr) * H_DIM + k0 + sc], &sAl[2048 + w * 512]);
    load_lds16(&Bh [(size_t)(n0 + sr) * H_DIM + k0 + sc],      &sBh[w * 512]);
    load_lds16(&Bh [(size_t)(n0 + 64 + sr) * H_DIM + k0 + sc], &sBh[2048 + w * 512]);
    load_lds16(&Blo[(size_t)(n0 + sr) * H_DIM + k0 + sc],      &sBl[w * 512]);
    load_lds16(&Blo[(size_t)(n0 + 64 + sr) * H_DIM + k0 + sc], &sBl[2048 + w * 512]);
    __syncthreads();

    bf16x8 ah[4], al[4], bh[4], bl[4];
#pragma unroll
    for (int mi = 0; mi < 4; mi++) {
      ah[mi] = *(const bf16x8*)&sAh[(wr * 64 + mi * 16 + lc) * BK + lg * 8];
      al[mi] = *(const bf16x8*)&sAl[(wr * 64 + mi * 16 + lc) * BK + lg * 8];
    }
#pragma unroll
    for (int nj = 0; nj < 4; nj++) {
      bh[nj] = *(const bf16x8*)&sBh[(wc * 64 + nj * 16 + lc) * BK + lg * 8];
      bl[nj] = *(const bf16x8*)&sBl[(wc * 64 + nj * 16 + lc) * BK + lg * 8];
    }
#pragma unroll
    for (int mi = 0; mi < 4; mi++)
#pragma unroll
      for (int nj = 0; nj < 4; nj++) {
        acc[mi][nj] = __builtin_amdgcn_mfma_f32_16x16x32_bf16(ah[mi], bh[nj], acc[mi][nj], 0, 0, 0);
        acc[mi][nj] = __builtin_amdgcn_mfma_f32_16x16x32_bf16(ah[mi], bl[nj], acc[mi][nj], 0, 0, 0);
        acc[mi][nj] = __builtin_amdgcn_mfma_f32_16x16x32_bf16(al[mi], bh[nj], acc[mi][nj], 0, 0, 0);
      }
  }

  const int nc0 = n0 + wc * 64;
  float bvals[4];
#pragma unroll
  for (int nj = 0; nj < 4; nj++) bvals[nj] = bias[nc0 + nj * 16 + lc];
#pragma unroll
  for (int mi = 0; mi < 4; mi++)
#pragma unroll
    for (int nj = 0; nj < 4; nj++)
#pragma unroll
      for (int r = 0; r < 4; r++) {
        int row = m0 + wr * 64 + mi * 16 + lg * 4 + r;
        out[(size_t)row * 1024 + nc0 + nj * 16 + lc] = acc[mi][nj][r] + bvals[nj];
      }
}

// ---------------------------------------------------------------------------
// MFMA flash attention (unchanged structure from round 2), epilogue now emits
// split-bf16 ctx (hi+lo) for the O-projection.
// ---------------------------------------------------------------------------
#define QB 128
#define KBT 64
#define LDK 72

__global__ __launch_bounds__(256) void attn_mfma_kernel(
    const u16* __restrict__ q, const u16* __restrict__ k,
    const u16* __restrict__ v, u16* __restrict__ ctxH, u16* __restrict__ ctxL) {
  __shared__ u16 Ks[KBT][LDK];
  __shared__ u16 Vt[HDIM][LDK];   // Vt[d][key]
  __shared__ u16 Qs[QB][LDK];     // Q at init; per-wave P buffer in loop

  const int tid = threadIdx.x;
  const int w  = tid >> 6;
  const int l  = tid & 63;
  const int lg = l >> 4;
  const int lc = l & 15;
  const int qt = blockIdx.x & 15;
  const int h  = (blockIdx.x >> 4) & 15;
  const int b  = blockIdx.x >> 8;

  {
    const size_t qbase = ((size_t)(b * SEQ + qt * QB)) * H_DIM + h * HDIM;
#pragma unroll
    for (int i = 0; i < 4; i++) {
      int c = tid + i * 256;
      int r = c >> 3, cc = c & 7;
      *(short8*)&Qs[r][cc * 8] = *(const short8*)&q[qbase + (size_t)r * H_DIM + cc * 8];
    }
  }
  __syncthreads();
  bf16x8 qf[2][2];
#pragma unroll
  for (int qi = 0; qi < 2; qi++)
#pragma unroll
    for (int kt = 0; kt < 2; kt++)
      qf[qi][kt] = *(bf16x8*)&Qs[w * 32 + qi * 16 + lc][kt * 32 + lg * 8];
  __syncthreads();

  f32x4 Oacc[2][4];
  float mrow[2][4], lrow[2][4];
#pragma unroll
  for (int qi = 0; qi < 2; qi++)
#pragma unroll
    for (int dj = 0; dj < 4; dj++)
      Oacc[qi][dj] = (f32x4){0.f, 0.f, 0.f, 0.f};
#pragma unroll
  for (int qi = 0; qi < 2; qi++)
#pragma unroll
    for (int r = 0; r < 4; r++) { mrow[qi][r] = -1e30f; lrow[qi][r] = 0.f; }

  u16* Pw = &Qs[w * 32][0];

  for (int t = 0; t < SEQ / KBT; t++) {
    __syncthreads();
    const size_t kvbase = ((size_t)(b * SEQ + t * KBT)) * H_DIM + h * HDIM;
#pragma unroll
    for (int i = 0; i < 2; i++) {
      int c = tid + i * 256;
      int r = c >> 3, cc = c & 7;
      *(short8*)&Ks[r][cc * 8] = *(const short8*)&k[kvbase + (size_t)r * H_DIM + cc * 8];
    }
#pragma unroll
    for (int i = 0; i < 2; i++) {
      int c = tid + i * 256;
      int key = c >> 3, cc = c & 7;
      short8 vv = *(const short8*)&v[kvbase + (size_t)key * H_DIM + cc * 8];
#pragma unroll
      for (int jj = 0; jj < 8; jj++) {
        int j = (jj + cc) & 7;
        Vt[cc * 8 + j][key] = (u16)vv[j];
      }
    }
    __syncthreads();

    f32x4 sc[2][4];
#pragma unroll
    for (int qi = 0; qi < 2; qi++)
#pragma unroll
      for (int kj = 0; kj < 4; kj++) {
        f32x4 s = (f32x4){0.f, 0.f, 0.f, 0.f};
#pragma unroll
        for (int kt = 0; kt < 2; kt++) {
          bf16x8 bfrag = *(bf16x8*)&Ks[kj * 16 + lc][kt * 32 + lg * 8];
          s = __builtin_amdgcn_mfma_f32_16x16x32_bf16(qf[qi][kt], bfrag, s, 0, 0, 0);
        }
        sc[qi][kj] = s;
      }

#pragma unroll
    for (int qi = 0; qi < 2; qi++) {
      float tm[4];
#pragma unroll
      for (int r = 0; r < 4; r++)
        tm[r] = fmaxf(fmaxf(sc[qi][0][r], sc[qi][1][r]),
                      fmaxf(sc[qi][2][r], sc[qi][3][r]));
#pragma unroll
      for (int mm = 1; mm < 16; mm <<= 1)
#pragma unroll
        for (int r = 0; r < 4; r++)
          tm[r] = fmaxf(tm[r], __shfl_xor(tm[r], mm));
#pragma unroll
      for (int r = 0; r < 4; r++) {
        float mnew = fmaxf(mrow[qi][r], tm[r]);
        float f = __expf(mrow[qi][r] - mnew);
        mrow[qi][r] = mnew;
        lrow[qi][r] *= f;
#pragma unroll
        for (int dj = 0; dj < 4; dj++) Oacc[qi][dj][r] *= f;
      }
#pragma unroll
      for (int kjj = 0; kjj < 4; kjj++) {
        int kj = (kjj + lg) & 3;
#pragma unroll
        for (int r = 0; r < 4; r++) {
          float p = __expf(sc[qi][kj][r] - mrow[qi][r]);
          lrow[qi][r] += p;
          Pw[(qi * 16 + lg * 4 + r) * LDK + kj * 16 + lc] = f2bf(p);
        }
      }
    }

    bf16x8 vfrag[4][2];
#pragma unroll
    for (int dj = 0; dj < 4; dj++)
#pragma unroll
      for (int kt = 0; kt < 2; kt++)
        vfrag[dj][kt] = *(bf16x8*)&Vt[dj * 16 + lc][kt * 32 + lg * 8];
#pragma unroll
    for (int qi = 0; qi < 2; qi++) {
      bf16x8 pa[2];
#pragma unroll
      for (int kt = 0; kt < 2; kt++)
        pa[kt] = *(bf16x8*)&Pw[(qi * 16 + lc) * LDK + kt * 32 + lg * 8];
#pragma unroll
      for (int dj = 0; dj < 4; dj++)
#pragma unroll
        for (int kt = 0; kt < 2; kt++)
          Oacc[qi][dj] = __builtin_amdgcn_mfma_f32_16x16x32_bf16(pa[kt], vfrag[dj][kt],
                                                                 Oacc[qi][dj], 0, 0, 0);
    }
  }

#pragma unroll
  for (int qi = 0; qi < 2; qi++) {
    float inv[4];
#pragma unroll
    for (int r = 0; r < 4; r++) {
      float ls = lrow[qi][r];
#pragma unroll
      for (int mm = 1; mm < 16; mm <<= 1) ls += __shfl_xor(ls, mm);
      inv[r] = 1.f / ls;
    }
#pragma unroll
    for (int dj = 0; dj < 4; dj++)
#pragma unroll
      for (int r = 0; r < 4; r++) {
        int qrow = b * SEQ + qt * QB + w * 32 + qi * 16 + lg * 4 + r;
        size_t idx = (size_t)qrow * H_DIM + h * HDIM + dj * 16 + lc;
        float val = Oacc[qi][dj][r] * inv[r];
        u16 hv = f2bf(val);
        ctxH[idx] = hv;
        ctxL[idx] = f2bf(val - bf2f(hv));
      }
  }
}

// ---------------------------------------------------------------------------
extern "C" void kernel_launch(void* const* d_in, const int* in_sizes, int n_in,
                              void* d_out, int out_size, void* d_ws, size_t ws_size,
                              hipStream_t stream) {
  const float* x  = (const float*)d_in[0];
  const float* Wq = (const float*)d_in[1];
  const float* bq = (const float*)d_in[2];
  const float* Wk = (const float*)d_in[3];
  const float* bk = (const float*)d_in[4];
  const float* Wv = (const float*)d_in[5];
  const float* bv = (const float*)d_in[6];
  const float* Wo = (const float*)d_in[7];
  const float* bo = (const float*)d_in[8];
  float* out = (float*)d_out;

  const size_t PL = (size_t)MTOT * H_DIM;   // 4M elems
  const size_t WN = (size_t)H_DIM * H_DIM;  // 1M elems
  u16* xb   = (u16*)d_ws;
  u16* W3   = xb + PL;           // [3072][1024]
  u16* qp   = W3 + 3 * WN;
  u16* kp   = qp + PL;
  u16* vp   = kp + PL;
  u16* ctxH = vp + PL;
  u16* ctxL = ctxH + PL;
  u16* WoH  = ctxL + PL;
  u16* WoL  = WoH + WN;

  const int n8x = (int)(PL / 8);   // 524288
  const int n8w = (int)(WN / 8);   // 131072

  conv_bf16<<<n8x / 256, 256, 0, stream>>>(x, xb, n8x);
  conv_bf16<<<n8w / 256, 256, 0, stream>>>(Wq, W3, n8w);
  conv_bf16<<<n8w / 256, 256, 0, stream>>>(Wk, W3 + WN, n8w);
  conv_bf16<<<n8w / 256, 256, 0, stream>>>(Wv, W3 + 2 * WN, n8w);
  conv_split<<<n8w / 256, 256, 0, stream>>>(Wo, WoH, WoL, n8w);

  gemm_qkv<<<dim3(3072 / 128, MTOT / 128), 256, 0, stream>>>(
      xb, W3, bq, bk, bv, qp, kp, vp);

  attn_mfma_kernel<<<dim3(BATCH * NHEAD * (SEQ / QB)), 256, 0, stream>>>(
      qp, kp, vp, ctxH, ctxL);

  gemm_oproj<<<dim3(1024 / 128, MTOT / 128), 256, 0, stream>>>(
      ctxH, ctxL, WoH, WoL, bo, out);
}

// Round 4
// 185.684 us; speedup vs baseline: 15.0314x; 2.2421x over previous
//
#include <hip/hip_runtime.h>
#include <hip/hip_bf16.h>

#define H_DIM 1024
#define NHEAD 16
#define HDIM  64
#define BATCH 2
#define SEQ   2048
#define MTOT  (BATCH*SEQ)   // 4096
#define LOG2E 1.4426950408889634f

typedef __bf16 bf16x8 __attribute__((ext_vector_type(8)));
typedef float  f32x4  __attribute__((ext_vector_type(4)));
typedef short  short8 __attribute__((ext_vector_type(8)));
typedef short  short4v __attribute__((ext_vector_type(4)));
typedef unsigned short u16;

static __device__ __forceinline__ u16 f2bf(float f) {
  __hip_bfloat16 h = __float2bfloat16(f);   // RNE
  return __builtin_bit_cast(u16, h);
}
static __device__ __forceinline__ float bf2f(u16 u) {
  return __builtin_bit_cast(float, (unsigned)u << 16);
}

// async global->LDS, 16B per lane. LDS dest = wave-uniform base + lane*16.
static __device__ __forceinline__ void load_lds16(const void* g, void* l) {
  __builtin_amdgcn_global_load_lds(
      (const __attribute__((address_space(1))) unsigned int*)g,
      (__attribute__((address_space(3))) unsigned int*)l, 16, 0, 0);
}

// ---------------------------------------------------------------------------
// fp32 -> bf16 conversion (8 elems/thread)
// ---------------------------------------------------------------------------
__global__ __launch_bounds__(256) void conv_bf16(
    const float* __restrict__ in, u16* __restrict__ out, int n8) {
  int i = blockIdx.x * 256 + threadIdx.x;
  if (i >= n8) return;
  float4 a = ((const float4*)in)[i * 2];
  float4 b = ((const float4*)in)[i * 2 + 1];
  union { u16 u[8]; short8 s; } r;
  r.u[0] = f2bf(a.x); r.u[1] = f2bf(a.y); r.u[2] = f2bf(a.z); r.u[3] = f2bf(a.w);
  r.u[4] = f2bf(b.x); r.u[5] = f2bf(b.y); r.u[6] = f2bf(b.z); r.u[7] = f2bf(b.w);
  *(short8*)&out[i * 8] = r.s;
}

// fp32 -> split bf16 (hi + lo), 8 elems/thread
__global__ __launch_bounds__(256) void conv_split(
    const float* __restrict__ in, u16* __restrict__ hi, u16* __restrict__ lo, int n8) {
  int i = blockIdx.x * 256 + threadIdx.x;
  if (i >= n8) return;
  float v[8];
  float4 a = ((const float4*)in)[i * 2];
  float4 b = ((const float4*)in)[i * 2 + 1];
  v[0] = a.x; v[1] = a.y; v[2] = a.z; v[3] = a.w;
  v[4] = b.x; v[5] = b.y; v[6] = b.z; v[7] = b.w;
  union { u16 u[8]; short8 s; } rh, rl;
#pragma unroll
  for (int j = 0; j < 8; j++) {
    u16 h = f2bf(v[j]);
    rh.u[j] = h;
    rl.u[j] = f2bf(v[j] - bf2f(h));
  }
  *(short8*)&hi[i * 8] = rh.s;
  *(short8*)&lo[i * 8] = rl.s;
}

// ---------------------------------------------------------------------------
// QKV fused GEMM (m97 structure): C[m][n] = sum_k X[m][k]*W3[n][k], bf16 MFMA.
// ---------------------------------------------------------------------------
#define BK 32

__global__ __launch_bounds__(256) void gemm_qkv(
    const u16* __restrict__ Xb, const u16* __restrict__ W3,
    const float* __restrict__ bq, const float* __restrict__ bk2,
    const float* __restrict__ bv,
    u16* __restrict__ qp, u16* __restrict__ kp, u16* __restrict__ vp) {
  __shared__ __align__(16) u16 Al[128 * BK];
  __shared__ __align__(16) u16 Bl[128 * BK];
  const int tid = threadIdx.x;
  const int w = tid >> 6, l = tid & 63, lg = l >> 4, lc = l & 15;
  const int wr = w >> 1, wc = w & 1;
  const int m0 = blockIdx.y * 128, n0 = blockIdx.x * 128;
  const int sr = w * 16 + (l >> 2);
  const int sc = (l & 3) * 8;

  f32x4 acc[4][4];
#pragma unroll
  for (int i = 0; i < 4; i++)
#pragma unroll
    for (int j = 0; j < 4; j++) acc[i][j] = (f32x4){0.f, 0.f, 0.f, 0.f};

  for (int k0 = 0; k0 < H_DIM; k0 += BK) {
    __syncthreads();
    load_lds16(&Xb[(size_t)(m0 + sr) * H_DIM + k0 + sc],      &Al[w * 512]);
    load_lds16(&Xb[(size_t)(m0 + 64 + sr) * H_DIM + k0 + sc], &Al[2048 + w * 512]);
    load_lds16(&W3[(size_t)(n0 + sr) * H_DIM + k0 + sc],      &Bl[w * 512]);
    load_lds16(&W3[(size_t)(n0 + 64 + sr) * H_DIM + k0 + sc], &Bl[2048 + w * 512]);
    __syncthreads();

    bf16x8 af[4], bfr[4];
#pragma unroll
    for (int mi = 0; mi < 4; mi++)
      af[mi] = *(const bf16x8*)&Al[(wr * 64 + mi * 16 + lc) * BK + lg * 8];
#pragma unroll
    for (int nj = 0; nj < 4; nj++)
      bfr[nj] = *(const bf16x8*)&Bl[(wc * 64 + nj * 16 + lc) * BK + lg * 8];
#pragma unroll
    for (int mi = 0; mi < 4; mi++)
#pragma unroll
      for (int nj = 0; nj < 4; nj++)
        acc[mi][nj] = __builtin_amdgcn_mfma_f32_16x16x32_bf16(af[mi], bfr[nj],
                                                              acc[mi][nj], 0, 0, 0);
  }

  const int np = n0 >> 10;
  u16* outp = np == 0 ? qp : (np == 1 ? kp : vp);
  const float* bias = np == 0 ? bq : (np == 1 ? bk2 : bv);
  // q gets 1/sqrt(64) * log2(e) folded in (softmax runs in log2 domain)
  const float scale = np == 0 ? (0.125f * LOG2E) : 1.0f;
  const int nc0 = (n0 & 1023) + wc * 64;
  float bvals[4];
#pragma unroll
  for (int nj = 0; nj < 4; nj++) bvals[nj] = bias[nc0 + nj * 16 + lc];
#pragma unroll
  for (int mi = 0; mi < 4; mi++)
#pragma unroll
    for (int nj = 0; nj < 4; nj++)
#pragma unroll
      for (int r = 0; r < 4; r++) {
        int row = m0 + wr * 64 + mi * 16 + lg * 4 + r;
        outp[(size_t)row * 1024 + nc0 + nj * 16 + lc] =
            f2bf((acc[mi][nj][r] + bvals[nj]) * scale);
      }
}

// ---------------------------------------------------------------------------
// O-projection, split-bf16 (hi+lo): out = Ah@Bh + Ah@Bl + Al@Bh + bias.
// ---------------------------------------------------------------------------
__global__ __launch_bounds__(256) void gemm_oproj(
    const u16* __restrict__ Ah, const u16* __restrict__ Alo,
    const u16* __restrict__ Bh, const u16* __restrict__ Blo,
    const float* __restrict__ bias, float* __restrict__ out) {
  __shared__ __align__(16) u16 sAh[128 * BK];
  __shared__ __align__(16) u16 sAl[128 * BK];
  __shared__ __align__(16) u16 sBh[128 * BK];
  __shared__ __align__(16) u16 sBl[128 * BK];
  const int tid = threadIdx.x;
  const int w = tid >> 6, l = tid & 63, lg = l >> 4, lc = l & 15;
  const int wr = w >> 1, wc = w & 1;
  const int m0 = blockIdx.y * 128, n0 = blockIdx.x * 128;
  const int sr = w * 16 + (l >> 2);
  const int sc = (l & 3) * 8;

  f32x4 acc[4][4];
#pragma unroll
  for (int i = 0; i < 4; i++)
#pragma unroll
    for (int j = 0; j < 4; j++) acc[i][j] = (f32x4){0.f, 0.f, 0.f, 0.f};

  for (int k0 = 0; k0 < H_DIM; k0 += BK) {
    __syncthreads();
    load_lds16(&Ah [(size_t)(m0 + sr) * H_DIM + k0 + sc],      &sAh[w * 512]);
    load_lds16(&Ah [(size_t)(m0 + 64 + sr) * H_DIM + k0 + sc], &sAh[2048 + w * 512]);
    load_lds16(&Alo[(size_t)(m0 + sr) * H_DIM + k0 + sc],      &sAl[w * 512]);
    load_lds16(&Alo[(size_t)(m0 + 64 + sr) * H_DIM + k0 + sc], &sAl[2048 + w * 512]);
    load_lds16(&Bh [(size_t)(n0 + sr) * H_DIM + k0 + sc],      &sBh[w * 512]);
    load_lds16(&Bh [(size_t)(n0 + 64 + sr) * H_DIM + k0 + sc], &sBh[2048 + w * 512]);
    load_lds16(&Blo[(size_t)(n0 + sr) * H_DIM + k0 + sc],      &sBl[w * 512]);
    load_lds16(&Blo[(size_t)(n0 + 64 + sr) * H_DIM + k0 + sc], &sBl[2048 + w * 512]);
    __syncthreads();

    bf16x8 ah[4], al[4], bh[4], bl[4];
#pragma unroll
    for (int mi = 0; mi < 4; mi++) {
      ah[mi] = *(const bf16x8*)&sAh[(wr * 64 + mi * 16 + lc) * BK + lg * 8];
      al[mi] = *(const bf16x8*)&sAl[(wr * 64 + mi * 16 + lc) * BK + lg * 8];
    }
#pragma unroll
    for (int nj = 0; nj < 4; nj++) {
      bh[nj] = *(const bf16x8*)&sBh[(wc * 64 + nj * 16 + lc) * BK + lg * 8];
      bl[nj] = *(const bf16x8*)&sBl[(wc * 64 + nj * 16 + lc) * BK + lg * 8];
    }
#pragma unroll
    for (int mi = 0; mi < 4; mi++)
#pragma unroll
      for (int nj = 0; nj < 4; nj++) {
        acc[mi][nj] = __builtin_amdgcn_mfma_f32_16x16x32_bf16(ah[mi], bh[nj], acc[mi][nj], 0, 0, 0);
        acc[mi][nj] = __builtin_amdgcn_mfma_f32_16x16x32_bf16(ah[mi], bl[nj], acc[mi][nj], 0, 0, 0);
        acc[mi][nj] = __builtin_amdgcn_mfma_f32_16x16x32_bf16(al[mi], bh[nj], acc[mi][nj], 0, 0, 0);
      }
  }

  const int nc0 = n0 + wc * 64;
  float bvals[4];
#pragma unroll
  for (int nj = 0; nj < 4; nj++) bvals[nj] = bias[nc0 + nj * 16 + lc];
#pragma unroll
  for (int mi = 0; mi < 4; mi++)
#pragma unroll
    for (int nj = 0; nj < 4; nj++)
#pragma unroll
      for (int r = 0; r < 4; r++) {
        int row = m0 + wr * 64 + mi * 16 + lg * 4 + r;
        out[(size_t)row * 1024 + nc0 + nj * 16 + lc] = acc[mi][nj][r] + bvals[nj];
      }
}

// ---------------------------------------------------------------------------
// Flash attention v2: swapped QK^T + O^T PV. 256 thr = 4 waves, 64 q-rows per
// block (16/wave, q = lane&15). KV tiles of 64. Scores arrive pre-scaled by
// log2e/8 (folded into Q projection); softmax in log2 domain with defer-max.
//   QK: S^T = mfma(A=K, B=Q) -> lane holds k = kj*16+lg*4+r for q = lc.
//   PV: O^T = mfma(A=V^T, B=P) -> lane holds d = dj*16+lg*4+r for q = lc.
// V LDS layout: Vt[d][key] row stride 120 u16 + per-row skew 8*(d>>3) u16
//   -> conflict-free compile-time-indexed b16 scatter writes + b128 reads.
// ---------------------------------------------------------------------------
#define RESCALE_THR 8.0f

__global__ __launch_bounds__(256, 4) void attn_mfma2(
    const u16* __restrict__ q, const u16* __restrict__ k,
    const u16* __restrict__ v, u16* __restrict__ ctxH, u16* __restrict__ ctxL) {
  __shared__ __align__(16) u16 Ks[64 * 72];      // [key][d] pad 72
  __shared__ __align__(16) u16 Vt[64 * 120];     // [d][key] stride 120 + skew
  __shared__ __align__(16) u16 Pws[4][16 * 72];  // per-wave [q][k] pad 72

  const int tid = threadIdx.x;
  const int w = tid >> 6, l = tid & 63, lg = l >> 4, lc = l & 15;
  const int qt = blockIdx.x & 31;          // SEQ/64
  const int h  = (blockIdx.x >> 5) & 15;
  const int b  = blockIdx.x >> 9;
  const size_t row0 = (size_t)(b * SEQ);

  // Q fragments direct from global (each row read once)
  bf16x8 qf[2];
  {
    const u16* qp = q + (row0 + qt * 64 + w * 16 + lc) * H_DIM + h * HDIM + lg * 8;
    qf[0] = *(const bf16x8*)(qp);
    qf[1] = *(const bf16x8*)(qp + 32);
  }

  // staging: thread covers chunks (key=skey, key+32) x (8 d-values at sd8*8)
  const int skey = tid >> 3, sd8 = tid & 7;
  const u16* kbase = k + row0 * H_DIM + h * HDIM;
  const u16* vbase = v + row0 * H_DIM + h * HDIM;
  short8 rK[2], rV[2];
  {
    size_t o = (size_t)skey * H_DIM + sd8 * 8;
    rK[0] = *(const short8*)(kbase + o);
    rK[1] = *(const short8*)(kbase + o + 32 * H_DIM);
    rV[0] = *(const short8*)(vbase + o);
    rV[1] = *(const short8*)(vbase + o + 32 * H_DIM);
  }

  f32x4 Oacc[4];
#pragma unroll
  for (int dj = 0; dj < 4; dj++) Oacc[dj] = (f32x4){0.f, 0.f, 0.f, 0.f};
  float mS = -1e30f, lS = 0.f;

  // V scatter base: value j of chunk -> Vt[(sd8*8+j)*120 + key + sd8*8]
  const int vwb = (sd8 * 8) * 120 + skey + sd8 * 8;
  const int vskew = (lc >> 3) * 8;   // read-side skew piece from lc

  for (int t = 0; t < SEQ / 64; ++t) {
    __syncthreads();   // all reads of previous tile done
    // ---- write staged K (2x b128) ----
    *(short8*)&Ks[skey * 72 + sd8 * 8] = rK[0];
    *(short8*)&Ks[(skey + 32) * 72 + sd8 * 8] = rK[1];
    // ---- write staged V: 16 compile-time-indexed b16 scatter stores ----
    {
      const unsigned* wv0 = (const unsigned*)&rV[0];
      const unsigned* wv1 = (const unsigned*)&rV[1];
#pragma unroll
      for (int j2 = 0; j2 < 4; j2++) {
        unsigned w0 = wv0[j2], w1 = wv1[j2];
        Vt[vwb + (2 * j2) * 120]      = (u16)w0;
        Vt[vwb + (2 * j2 + 1) * 120]  = (u16)(w0 >> 16);
        Vt[vwb + 32 + (2 * j2) * 120]     = (u16)w1;
        Vt[vwb + 32 + (2 * j2 + 1) * 120] = (u16)(w1 >> 16);
      }
    }
    __syncthreads();
    // ---- T14: issue next tile's global loads (land during compute) ----
    if (t + 1 < SEQ / 64) {
      size_t o = (size_t)((t + 1) * 64 + skey) * H_DIM + sd8 * 8;
      rK[0] = *(const short8*)(kbase + o);
      rK[1] = *(const short8*)(kbase + o + 32 * H_DIM);
      rV[0] = *(const short8*)(vbase + o);
      rV[1] = *(const short8*)(vbase + o + 32 * H_DIM);
    }

    // ---- S^T = mfma(K, Q): p4[kj][r] = score(k = kj*16+lg*4+r, q = lc) ----
    f32x4 p4[4];
#pragma unroll
    for (int kj = 0; kj < 4; kj++) {
      f32x4 s = (f32x4){0.f, 0.f, 0.f, 0.f};
#pragma unroll
      for (int kt = 0; kt < 2; kt++) {
        bf16x8 af = *(const bf16x8*)&Ks[(kj * 16 + lc) * 72 + kt * 32 + lg * 8];
        s = __builtin_amdgcn_mfma_f32_16x16x32_bf16(af, qf[kt], s, 0, 0, 0);
      }
      p4[kj] = s;
    }

    // ---- online softmax (log2 domain), defer-max ----
    float tm = -1e30f;
#pragma unroll
    for (int kj = 0; kj < 4; kj++)
      tm = fmaxf(tm, fmaxf(fmaxf(p4[kj][0], p4[kj][1]), fmaxf(p4[kj][2], p4[kj][3])));
    tm = fmaxf(tm, __shfl_xor(tm, 16));
    tm = fmaxf(tm, __shfl_xor(tm, 32));
    if (!__all(tm <= mS + RESCALE_THR)) {
      float mnew = fmaxf(mS, tm);
      float f = exp2f(mS - mnew);
      lS *= f;
#pragma unroll
      for (int dj = 0; dj < 4; dj++) Oacc[dj] *= f;
      mS = mnew;
    }
    float ps = 0.f;
#pragma unroll
    for (int kj = 0; kj < 4; kj++) {
      short4v pw;
#pragma unroll
      for (int r = 0; r < 4; r++) {
        float p = exp2f(p4[kj][r] - mS);
        ps += p;
        pw[r] = (short)f2bf(p);
      }
      *(short4v*)&Pws[w][lc * 72 + kj * 16 + lg * 4] = pw;   // b64 write
    }
    ps += __shfl_xor(ps, 16);
    ps += __shfl_xor(ps, 32);
    lS += ps;

    // ---- O^T += mfma(V^T, P) ----
    bf16x8 pb[2];
    pb[0] = *(const bf16x8*)&Pws[w][lc * 72 + lg * 8];
    pb[1] = *(const bf16x8*)&Pws[w][lc * 72 + 32 + lg * 8];
#pragma unroll
    for (int dj = 0; dj < 4; dj++) {
      // row = dj*16+lc, skew = (row>>3)*8 = dj*16 + (lc>>3)*8
      const int vb = (dj * 16 + lc) * 120 + dj * 16 + vskew;
      bf16x8 vf0 = *(const bf16x8*)&Vt[vb + lg * 8];
      bf16x8 vf1 = *(const bf16x8*)&Vt[vb + 32 + lg * 8];
      Oacc[dj] = __builtin_amdgcn_mfma_f32_16x16x32_bf16(vf0, pb[0], Oacc[dj], 0, 0, 0);
      Oacc[dj] = __builtin_amdgcn_mfma_f32_16x16x32_bf16(vf1, pb[1], Oacc[dj], 0, 0, 0);
    }
  }

  // ---- epilogue: normalize, split-bf16 store (O^T: d = dj*16+lg*4+r, q = lc) ----
  float inv = 1.f / lS;
  size_t obase = (row0 + qt * 64 + w * 16 + lc) * H_DIM + h * HDIM;
#pragma unroll
  for (int dj = 0; dj < 4; dj++) {
    short4v hv, lv;
#pragma unroll
    for (int r = 0; r < 4; r++) {
      float val = Oacc[dj][r] * inv;
      u16 hb = f2bf(val);
      hv[r] = (short)hb;
      lv[r] = (short)f2bf(val - bf2f(hb));
    }
    *(short4v*)&ctxH[obase + dj * 16 + lg * 4] = hv;
    *(short4v*)&ctxL[obase + dj * 16 + lg * 4] = lv;
  }
}

// ---------------------------------------------------------------------------
extern "C" void kernel_launch(void* const* d_in, const int* in_sizes, int n_in,
                              void* d_out, int out_size, void* d_ws, size_t ws_size,
                              hipStream_t stream) {
  const float* x  = (const float*)d_in[0];
  const float* Wq = (const float*)d_in[1];
  const float* bq = (const float*)d_in[2];
  const float* Wk = (const float*)d_in[3];
  const float* bk = (const float*)d_in[4];
  const float* Wv = (const float*)d_in[5];
  const float* bv = (const float*)d_in[6];
  const float* Wo = (const float*)d_in[7];
  const float* bo = (const float*)d_in[8];
  float* out = (float*)d_out;

  const size_t PL = (size_t)MTOT * H_DIM;   // 4M elems
  const size_t WN = (size_t)H_DIM * H_DIM;  // 1M elems
  u16* xb   = (u16*)d_ws;
  u16* W3   = xb + PL;
  u16* qp   = W3 + 3 * WN;
  u16* kp   = qp + PL;
  u16* vp   = kp + PL;
  u16* ctxH = vp + PL;
  u16* ctxL = ctxH + PL;
  u16* WoH  = ctxL + PL;
  u16* WoL  = WoH + WN;

  const int n8x = (int)(PL / 8);
  const int n8w = (int)(WN / 8);

  conv_bf16<<<n8x / 256, 256, 0, stream>>>(x, xb, n8x);
  conv_bf16<<<n8w / 256, 256, 0, stream>>>(Wq, W3, n8w);
  conv_bf16<<<n8w / 256, 256, 0, stream>>>(Wk, W3 + WN, n8w);
  conv_bf16<<<n8w / 256, 256, 0, stream>>>(Wv, W3 + 2 * WN, n8w);
  conv_split<<<n8w / 256, 256, 0, stream>>>(Wo, WoH, WoL, n8w);

  gemm_qkv<<<dim3(3072 / 128, MTOT / 128), 256, 0, stream>>>(
      xb, W3, bq, bk, bv, qp, kp, vp);

  attn_mfma2<<<dim3(BATCH * NHEAD * (SEQ / 64)), 256, 0, stream>>>(
      qp, kp, vp, ctxH, ctxL);

  gemm_oproj<<<dim3(1024 / 128, MTOT / 128), 256, 0, stream>>>(
      ctxH, ctxL, WoH, WoL, bo, out);
}